// Round 6
// baseline (157.331 us; speedup 1.0000x reference)
//
#include <hip/hip_runtime.h>
#include <math.h>

#define HH 512
#define WW 512
#define PHH 16
#define PWW 16
#define QQ 3
#define NHH 32
#define NWW 32
#define PP 1024
#define BB 64

// Compiler-only memory fence (IR + sched chain edges). No sched_barrier(0):
// that pinned code motion and spiked register pressure (rounds 3/4).
__device__ __forceinline__ void wfence() {
  asm volatile("" ::: "memory");
}

// Butterfly with COMPILE-TIME twiddle index T (0..7), radix-2 DIT, n=16.
template <int SGN, int T>
__device__ __forceinline__ void bfly(float& ar, float& ai, float& br, float& bi) {
  float tr, ti;
  if constexpr (T == 0) {
    tr = br;
    ti = bi;
  } else if constexpr (T == 4) {
    if constexpr (SGN > 0) { tr = bi;  ti = -br; }
    else                   { tr = -bi; ti = br;  }
  } else if constexpr (T == 2) {
    constexpr float c = 0.70710678118654752440f;
    if constexpr (SGN > 0) { tr = c * (br + bi); ti = c * (bi - br); }
    else                   { tr = c * (br - bi); ti = c * (bi + br); }
  } else if constexpr (T == 6) {
    constexpr float c = 0.70710678118654752440f;
    if constexpr (SGN > 0) { tr = c * (bi - br);  ti = -c * (br + bi); }
    else                   { tr = -c * (br + bi); ti = c * (br - bi);  }
  } else {
    constexpr float c1 = 0.92387953251128675613f;   // cos(pi/8)
    constexpr float s1 = 0.38268343236508977173f;   // sin(pi/8)
    constexpr float wr = (T == 1) ? c1 : (T == 3) ? s1 : (T == 5) ? -s1 : -c1;
    constexpr float wi0 = (T == 1) ? -s1 : (T == 3) ? -c1 : (T == 5) ? -c1 : -s1;
    constexpr float wi = (SGN > 0) ? wi0 : -wi0;
    tr = br * wr - bi * wi;
    ti = br * wi + bi * wr;
  }
  br = ar - tr;
  bi = ai - ti;
  ar = ar + tr;
  ai = ai + ti;
}

// Fully-unrolled in-register 16-point complex FFT.
template <int SGN>
__device__ __forceinline__ void fft16(float re[16], float im[16]) {
#define SW_(a, b)                              \
  { float t = re[a]; re[a] = re[b]; re[b] = t; \
    t = im[a]; im[a] = im[b]; im[b] = t; }
  SW_(1, 8) SW_(2, 4) SW_(3, 12) SW_(5, 10) SW_(7, 14) SW_(11, 13)
#undef SW_
#define BF_(a, b, T) bfly<SGN, T>(re[a], im[a], re[b], im[b]);
  // len=2
  BF_(0, 1, 0) BF_(2, 3, 0) BF_(4, 5, 0) BF_(6, 7, 0)
  BF_(8, 9, 0) BF_(10, 11, 0) BF_(12, 13, 0) BF_(14, 15, 0)
  // len=4
  BF_(0, 2, 0) BF_(1, 3, 4) BF_(4, 6, 0) BF_(5, 7, 4)
  BF_(8, 10, 0) BF_(9, 11, 4) BF_(12, 14, 0) BF_(13, 15, 4)
  // len=8
  BF_(0, 4, 0) BF_(1, 5, 2) BF_(2, 6, 4) BF_(3, 7, 6)
  BF_(8, 12, 0) BF_(9, 13, 2) BF_(10, 14, 4) BF_(11, 15, 6)
  // len=16
  BF_(0, 8, 0) BF_(1, 9, 1) BF_(2, 10, 2) BF_(3, 11, 3)
  BF_(4, 12, 4) BF_(5, 13, 5) BF_(6, 14, 6) BF_(7, 15, 7)
#undef BF_
}

// One block per patch p (1024 blocks): round-5 evidence showed 4096 tiny WGs
// were workgroup-dispatch-rate-bound (~14ns/WG; achieved occupancy 24% with a
// 100% theoretical cap, dur pinned ~57-60us regardless of per-block work).
// Each block loops 4 batch-chunks of 16; group g = tid>>4 -> batch 16*i+g,
// thread r = tid&15 -> row r. S computed ONCE per patch (amortized 4x).
// Next chunk's x-rows are prefetched into registers at iteration top (named
// arrays + fully unrolled loop: static indexing, no scratch).
// Transposes: wave-local (group = quarter-wave), stride-17 scalar, proven 0
// bank conflicts. One __syncthreads total (S_lds).
// amdgpu_waves_per_eu(1,3): VGPR budget ~85 (empirical budget=256/max_waves);
// live set ~70 with prefetch. (1,4)'s budget 64 would spill.
__global__ __launch_bounds__(256)
__attribute__((amdgpu_waves_per_eu(1, 3)))
void psm_kernel(
    const float* __restrict__ x, const float* __restrict__ logits,
    const float* __restrict__ mu, const float* __restrict__ sigma,
    const float* __restrict__ bias, float* __restrict__ out) {
  __shared__ float S_lds[256];
  __shared__ float tbuf[16 * 272];  // 16 groups, 16 rows, stride 17

  const int tid = threadIdx.x;
  const int p = blockIdx.x;
  const int g = tid >> 4;
  const int r = tid & 15;
  const int nh = p >> 5;
  const int nw = p & 31;

  // Per-thread row base within one image; batch b adds b*H*W.
  const size_t rowbase =
      (size_t)(nh * PHH + r) * WW + (size_t)(nw * PWW);

  // ---- Issue chunk-0 loads FIRST: latency hides under Phase A ----
  float re[16], im[16];
  {
    const float* xrow = x + (size_t)g * (HH * WW) + rowbase;
#pragma unroll
    for (int c4 = 0; c4 < 4; ++c4) {
      const float4 v = ((const float4*)xrow)[c4];
      re[c4 * 4 + 0] = v.x;
      re[c4 * 4 + 1] = v.y;
      re[c4 * 4 + 2] = v.z;
      re[c4 * 4 + 3] = v.w;
    }
  }

  // ---- Phase A: spectral filter S for this patch into LDS (once) ----
  {
    const int fy_i = tid >> 4;
    const int fx_i = tid & 15;
    const float fy = (float)(fy_i < 8 ? fy_i : fy_i - 16) * (1.0f / 16.0f);
    const float fx = (float)(fx_i < 8 ? fx_i : fx_i - 16) * (1.0f / 16.0f);
    const float l0 = logits[p * QQ + 0];
    const float l1 = logits[p * QQ + 1];
    const float l2 = logits[p * QQ + 2];
    const float lm = fmaxf(l0, fmaxf(l1, l2));
    const float e0 = __expf(l0 - lm);
    const float e1 = __expf(l1 - lm);
    const float e2 = __expf(l2 - lm);
    const float inv = 1.0f / (e0 + e1 + e2);
    const float wq[3] = {e0 * inv, e1 * inv, e2 * inv};
    float s = 0.0f;
#pragma unroll
    for (int q = 0; q < QQ; ++q) {
      const float muy = mu[(p * QQ + q) * 2 + 0];
      const float mux = mu[(p * QQ + q) * 2 + 1];
      const float isy = 1.0f / sigma[(p * QQ + q) * 2 + 0];
      const float isx = 1.0f / sigma[(p * QQ + q) * 2 + 1];
      const float dy1 = (fy - muy) * isy;
      const float dx1 = (fx - mux) * isx;
      const float dy2 = (fy + muy) * isy;
      const float dx2 = (fx + mux) * isx;
      const float g1 = __expf(-0.5f * (dy1 * dy1 + dx1 * dx1));
      const float g2 = __expf(-0.5f * (dy2 * dy2 + dx2 * dx2));
      s += wq[q] * (g1 + g2);
    }
    S_lds[tid] = (s + 1e-6f) * (1.0f / 256.0f);
  }
  __syncthreads();  // the ONLY block barrier

  float* m = &tbuf[g * 272];
  const float* brow = bias + (size_t)p * 256 + (size_t)r * 16;

#pragma unroll
  for (int i = 0; i < 4; ++i) {
    wfence();  // loop-boundary LDS reuse safety (cross-lane, wave-internal)

    // ---- Prefetch next chunk's row into registers (issue early; the
    //      s_waitcnt lands at the copy/use in the NEXT iteration) ----
    float nre[16];
    if (i < 3) {
      const float* xnext =
          x + (size_t)(16 * (i + 1) + g) * (HH * WW) + rowbase;
#pragma unroll
      for (int c4 = 0; c4 < 4; ++c4) {
        const float4 v = ((const float4*)xnext)[c4];
        nre[c4 * 4 + 0] = v.x;
        nre[c4 * 4 + 1] = v.y;
        nre[c4 * 4 + 2] = v.z;
        nre[c4 * 4 + 3] = v.w;
      }
    }

    // ---- Forward row FFT (im starts at literal zero) ----
#pragma unroll
    for (int c = 0; c < 16; ++c) im[c] = 0.0f;
    fft16<1>(re, im);

    // ---- Transpose via wave-local LDS ----
#pragma unroll
    for (int c = 0; c < 16; ++c) m[r * 17 + c] = re[c];
    wfence();
#pragma unroll
    for (int k = 0; k < 16; ++k) re[k] = m[k * 17 + r];
    wfence();
#pragma unroll
    for (int c = 0; c < 16; ++c) m[r * 17 + c] = im[c];
    wfence();
#pragma unroll
    for (int k = 0; k < 16; ++k) im[k] = m[k * 17 + r];
    wfence();

    // ---- Column FFT, multiply by S, inverse column FFT ----
    fft16<1>(re, im);
#pragma unroll
    for (int k = 0; k < 16; ++k) {
      const float s = S_lds[k * 16 + r];
      re[k] *= s;
      im[k] *= s;
    }
    fft16<-1>(re, im);

    // ---- Transpose back ----
#pragma unroll
    for (int k = 0; k < 16; ++k) m[k * 17 + r] = re[k];
    wfence();
#pragma unroll
    for (int c = 0; c < 16; ++c) re[c] = m[r * 17 + c];
    wfence();
#pragma unroll
    for (int k = 0; k < 16; ++k) m[k * 17 + r] = im[k];
    wfence();
#pragma unroll
    for (int c = 0; c < 16; ++c) im[c] = m[r * 17 + c];

    // ---- Inverse row FFT, real part + bias, store this chunk ----
    fft16<-1>(re, im);

    float* orow = out + (size_t)(16 * i + g) * (HH * WW) + rowbase;
#pragma unroll
    for (int c4 = 0; c4 < 4; ++c4) {
      const float4 bv = ((const float4*)brow)[c4];
      float4 o;
      o.x = re[c4 * 4 + 0] + bv.x;
      o.y = re[c4 * 4 + 1] + bv.y;
      o.z = re[c4 * 4 + 2] + bv.z;
      o.w = re[c4 * 4 + 3] + bv.w;
      ((float4*)orow)[c4] = o;
    }

    // ---- Rotate prefetched data into place (register rename, static) ----
    if (i < 3) {
#pragma unroll
      for (int c = 0; c < 16; ++c) re[c] = nre[c];
    }
  }
}

extern "C" void kernel_launch(void* const* d_in, const int* in_sizes, int n_in,
                              void* d_out, int out_size, void* d_ws,
                              size_t ws_size, hipStream_t stream) {
  (void)in_sizes;
  (void)n_in;
  (void)out_size;
  (void)d_ws;
  (void)ws_size;
  const float* x = (const float*)d_in[0];
  const float* logits = (const float*)d_in[1];
  const float* mu = (const float*)d_in[2];
  const float* sigma = (const float*)d_in[3];
  const float* bias = (const float*)d_in[4];
  float* out = (float*)d_out;

  // One block per patch; each block loops 4 batch-chunks of 16.
  psm_kernel<<<dim3(PP), dim3(256), 0, stream>>>(x, logits, mu, sigma,
                                                 bias, out);
}

// Round 7
// 153.075 us; speedup vs baseline: 1.0278x; 1.0278x over previous
//
#include <hip/hip_runtime.h>
#include <math.h>

#define HH 512
#define WW 512
#define PHH 16
#define PWW 16
#define QQ 3
#define NHH 32
#define NWW 32
#define PP 1024
#define BB 64

// Compiler-only memory fence (IR + sched chain edges). No sched_barrier(0):
// that pinned code motion and spiked register pressure (rounds 3/4).
__device__ __forceinline__ void wfence() {
  asm volatile("" ::: "memory");
}

// Butterfly with COMPILE-TIME twiddle index T (0..7), radix-2 DIT, n=16.
template <int SGN, int T>
__device__ __forceinline__ void bfly(float& ar, float& ai, float& br, float& bi) {
  float tr, ti;
  if constexpr (T == 0) {
    tr = br;
    ti = bi;
  } else if constexpr (T == 4) {
    if constexpr (SGN > 0) { tr = bi;  ti = -br; }
    else                   { tr = -bi; ti = br;  }
  } else if constexpr (T == 2) {
    constexpr float c = 0.70710678118654752440f;
    if constexpr (SGN > 0) { tr = c * (br + bi); ti = c * (bi - br); }
    else                   { tr = c * (br - bi); ti = c * (bi + br); }
  } else if constexpr (T == 6) {
    constexpr float c = 0.70710678118654752440f;
    if constexpr (SGN > 0) { tr = c * (bi - br);  ti = -c * (br + bi); }
    else                   { tr = -c * (br + bi); ti = c * (br - bi);  }
  } else {
    constexpr float c1 = 0.92387953251128675613f;   // cos(pi/8)
    constexpr float s1 = 0.38268343236508977173f;   // sin(pi/8)
    constexpr float wr = (T == 1) ? c1 : (T == 3) ? s1 : (T == 5) ? -s1 : -c1;
    constexpr float wi0 = (T == 1) ? -s1 : (T == 3) ? -c1 : (T == 5) ? -c1 : -s1;
    constexpr float wi = (SGN > 0) ? wi0 : -wi0;
    tr = br * wr - bi * wi;
    ti = br * wi + bi * wr;
  }
  br = ar - tr;
  bi = ai - ti;
  ar = ar + tr;
  ai = ai + ti;
}

// Fully-unrolled in-register 16-point complex FFT.
template <int SGN>
__device__ __forceinline__ void fft16(float re[16], float im[16]) {
#define SW_(a, b)                              \
  { float t = re[a]; re[a] = re[b]; re[b] = t; \
    t = im[a]; im[a] = im[b]; im[b] = t; }
  SW_(1, 8) SW_(2, 4) SW_(3, 12) SW_(5, 10) SW_(7, 14) SW_(11, 13)
#undef SW_
#define BF_(a, b, T) bfly<SGN, T>(re[a], im[a], re[b], im[b]);
  // len=2
  BF_(0, 1, 0) BF_(2, 3, 0) BF_(4, 5, 0) BF_(6, 7, 0)
  BF_(8, 9, 0) BF_(10, 11, 0) BF_(12, 13, 0) BF_(14, 15, 0)
  // len=4
  BF_(0, 2, 0) BF_(1, 3, 4) BF_(4, 6, 0) BF_(5, 7, 4)
  BF_(8, 10, 0) BF_(9, 11, 4) BF_(12, 14, 0) BF_(13, 15, 4)
  // len=8
  BF_(0, 4, 0) BF_(1, 5, 2) BF_(2, 6, 4) BF_(3, 7, 6)
  BF_(8, 12, 0) BF_(9, 13, 2) BF_(10, 14, 4) BF_(11, 15, 6)
  // len=16
  BF_(0, 8, 0) BF_(1, 9, 1) BF_(2, 10, 2) BF_(3, 11, 3)
  BF_(4, 12, 4) BF_(5, 13, 5) BF_(6, 14, 6) BF_(7, 15, 7)
#undef BF_
}

// COMPLEX PACKING (round-7): x is real and S is exactly even-symmetric in FP
// (the +-mu Gaussian pair: (-f-mu)^2 == (f+mu)^2, g1+g2 commutes), so
// IFFT2(S o FFT2(x)) is real and for z = x_a + i*x_b:
//   IFFT2(S o FFT2(z)) = y_a + i*y_b   (linearity, S real)
// -> one complex pipeline filters TWO batch images; Re/Im split at the store.
// This halves FFT count, LDS transpose traffic, and S-multiplies. Round-5
// pipe model was VALU 21us + LDS 22us + HBM 21us executing ~serially (57us);
// this cuts the two compute pipes to ~11us each.
//
// Block: 256 threads = 16 groups x 16 rows. Grid 2048 = 1024 patches x
// 2 chunks of 32 images; group g -> image pair (32*chunk + 2g, +1).
// Transposes wave-local (group = quarter-wave), stride-17 scalar (0 conflicts
// proven r0/r3/r5). One __syncthreads total (S_lds).
// amdgpu_waves_per_eu(1,3): VGPR budget ~85; live set ~52-68 fits, no spill
// (rounds 5/6 evidence; (1,4)'s budget 64 spilled in rounds 2-4 variants).
__global__ __launch_bounds__(256)
__attribute__((amdgpu_waves_per_eu(1, 3)))
void psm_kernel(
    const float* __restrict__ x, const float* __restrict__ logits,
    const float* __restrict__ mu, const float* __restrict__ sigma,
    const float* __restrict__ bias, float* __restrict__ out) {
  __shared__ float S_lds[256];
  __shared__ float tbuf[16 * 272];  // 16 groups, 16 rows, stride 17

  const int tid = threadIdx.x;
  const int p = blockIdx.x >> 1;
  const int chunk = blockIdx.x & 1;
  const int g = tid >> 4;
  const int r = tid & 15;
  const int nh = p >> 5;
  const int nw = p & 31;

  const int b_re = chunk * 32 + 2 * g;  // even image of the pair
  // odd image = b_re + 1

  // Per-thread row base within one image; image b adds b*H*W.
  const size_t rowbase = (size_t)(nh * PHH + r) * WW + (size_t)(nw * PWW);
  const size_t off_re = (size_t)b_re * (HH * WW) + rowbase;

  // ---- Issue BOTH rows' loads FIRST: latency hides under Phase A ----
  float re[16], im[16];
  {
    const float* xa = x + off_re;
    const float* xb = xa + (size_t)(HH * WW);  // next image, same row
#pragma unroll
    for (int c4 = 0; c4 < 4; ++c4) {
      const float4 va = ((const float4*)xa)[c4];
      re[c4 * 4 + 0] = va.x;
      re[c4 * 4 + 1] = va.y;
      re[c4 * 4 + 2] = va.z;
      re[c4 * 4 + 3] = va.w;
    }
#pragma unroll
    for (int c4 = 0; c4 < 4; ++c4) {
      const float4 vb = ((const float4*)xb)[c4];
      im[c4 * 4 + 0] = vb.x;
      im[c4 * 4 + 1] = vb.y;
      im[c4 * 4 + 2] = vb.z;
      im[c4 * 4 + 3] = vb.w;
    }
  }

  // ---- Phase A: spectral filter S for this patch into LDS ----
  {
    const int fy_i = tid >> 4;
    const int fx_i = tid & 15;
    const float fy = (float)(fy_i < 8 ? fy_i : fy_i - 16) * (1.0f / 16.0f);
    const float fx = (float)(fx_i < 8 ? fx_i : fx_i - 16) * (1.0f / 16.0f);
    const float l0 = logits[p * QQ + 0];
    const float l1 = logits[p * QQ + 1];
    const float l2 = logits[p * QQ + 2];
    const float lm = fmaxf(l0, fmaxf(l1, l2));
    const float e0 = __expf(l0 - lm);
    const float e1 = __expf(l1 - lm);
    const float e2 = __expf(l2 - lm);
    const float inv = 1.0f / (e0 + e1 + e2);
    const float wq[3] = {e0 * inv, e1 * inv, e2 * inv};
    float s = 0.0f;
#pragma unroll
    for (int q = 0; q < QQ; ++q) {
      const float muy = mu[(p * QQ + q) * 2 + 0];
      const float mux = mu[(p * QQ + q) * 2 + 1];
      const float isy = 1.0f / sigma[(p * QQ + q) * 2 + 0];
      const float isx = 1.0f / sigma[(p * QQ + q) * 2 + 1];
      const float dy1 = (fy - muy) * isy;
      const float dx1 = (fx - mux) * isx;
      const float dy2 = (fy + muy) * isy;
      const float dx2 = (fx + mux) * isx;
      const float g1 = __expf(-0.5f * (dy1 * dy1 + dx1 * dx1));
      const float g2 = __expf(-0.5f * (dy2 * dy2 + dx2 * dx2));
      s += wq[q] * (g1 + g2);
    }
    // fold jitter and the ifft2 1/256 normalization into S
    S_lds[tid] = (s + 1e-6f) * (1.0f / 256.0f);
  }
  __syncthreads();  // the ONLY block barrier

  // ---- Forward row FFT (full complex: two packed real rows) ----
  fft16<1>(re, im);

  // ---- Transpose via wave-local LDS, single reused buffer ----
  float* m = &tbuf[g * 272];
#pragma unroll
  for (int c = 0; c < 16; ++c) m[r * 17 + c] = re[c];
  wfence();
#pragma unroll
  for (int k = 0; k < 16; ++k) re[k] = m[k * 17 + r];
  wfence();
#pragma unroll
  for (int c = 0; c < 16; ++c) m[r * 17 + c] = im[c];
  wfence();
#pragma unroll
  for (int k = 0; k < 16; ++k) im[k] = m[k * 17 + r];
  wfence();

  // ---- Column FFT, multiply by S, inverse column FFT ----
  fft16<1>(re, im);
#pragma unroll
  for (int k = 0; k < 16; ++k) {
    const float s = S_lds[k * 16 + r];
    re[k] *= s;
    im[k] *= s;
  }
  fft16<-1>(re, im);

  // ---- Transpose back ----
#pragma unroll
  for (int k = 0; k < 16; ++k) m[k * 17 + r] = re[k];
  wfence();
#pragma unroll
  for (int c = 0; c < 16; ++c) re[c] = m[r * 17 + c];
  wfence();
#pragma unroll
  for (int k = 0; k < 16; ++k) m[k * 17 + r] = im[k];
  wfence();
#pragma unroll
  for (int c = 0; c < 16; ++c) im[c] = m[r * 17 + c];

  // ---- Inverse row FFT; Re -> image b_re, Im -> image b_re+1; +bias ----
  fft16<-1>(re, im);

  const float* brow = bias + (size_t)p * 256 + (size_t)r * 16;
  float* oa = out + off_re;
  float* ob = oa + (size_t)(HH * WW);
#pragma unroll
  for (int c4 = 0; c4 < 4; ++c4) {
    const float4 bv = ((const float4*)brow)[c4];
    float4 o1, o2;
    o1.x = re[c4 * 4 + 0] + bv.x;
    o1.y = re[c4 * 4 + 1] + bv.y;
    o1.z = re[c4 * 4 + 2] + bv.z;
    o1.w = re[c4 * 4 + 3] + bv.w;
    o2.x = im[c4 * 4 + 0] + bv.x;
    o2.y = im[c4 * 4 + 1] + bv.y;
    o2.z = im[c4 * 4 + 2] + bv.z;
    o2.w = im[c4 * 4 + 3] + bv.w;
    ((float4*)oa)[c4] = o1;
    ((float4*)ob)[c4] = o2;
  }
}

extern "C" void kernel_launch(void* const* d_in, const int* in_sizes, int n_in,
                              void* d_out, int out_size, void* d_ws,
                              size_t ws_size, hipStream_t stream) {
  (void)in_sizes;
  (void)n_in;
  (void)out_size;
  (void)d_ws;
  (void)ws_size;
  const float* x = (const float*)d_in[0];
  const float* logits = (const float*)d_in[1];
  const float* mu = (const float*)d_in[2];
  const float* sigma = (const float*)d_in[3];
  const float* bias = (const float*)d_in[4];
  float* out = (float*)d_out;

  // 1024 patches x 2 chunks of 32 images (16 complex-packed pairs each).
  psm_kernel<<<dim3(PP * 2), dim3(256), 0, stream>>>(x, logits, mu, sigma,
                                                     bias, out);
}

// Round 9
// 132.960 us; speedup vs baseline: 1.1833x; 1.1513x over previous
//
#include <hip/hip_runtime.h>
#include <math.h>

#define HH 512
#define WW 512
#define QQ 3

// LDS strip geometry: 16 rows x 256 px, row stride 260 floats (+4 pad).
// Row access  [r][nw*16+c]: banks (4r + 16g + c) -> 2 lanes/bank (free).
// Col access  [j][nw*16+k]: per-instr banks spread across 64 lanes (free).
#define SROW 260
// ytab per-patch stride: 6 vectors x 16 + 8 pad -> group offsets 0/8/16/24.
#define YROW 104

// Compiler-only memory fence: orders LDS ops (IR + sched chain edges) without
// pinning all code motion (sched_barrier(0) caused pressure spills, r3/r4).
// HW guarantee: one wave's LDS ops complete in issue order -> cross-lane
// write->read within a wave needs no s_barrier (proven r5: absmax clean).
__device__ __forceinline__ void wfence() { asm volatile("" ::: "memory"); }

// Butterfly with compile-time twiddle index T (0..7), radix-2 DIT, n=16.
template <int SGN, int T>
__device__ __forceinline__ void bfly(float& ar, float& ai, float& br, float& bi) {
  float tr, ti;
  if constexpr (T == 0) {
    tr = br;
    ti = bi;
  } else if constexpr (T == 4) {
    if constexpr (SGN > 0) { tr = bi;  ti = -br; }
    else                   { tr = -bi; ti = br;  }
  } else if constexpr (T == 2) {
    constexpr float c = 0.70710678118654752440f;
    if constexpr (SGN > 0) { tr = c * (br + bi); ti = c * (bi - br); }
    else                   { tr = c * (br - bi); ti = c * (bi + br); }
  } else if constexpr (T == 6) {
    constexpr float c = 0.70710678118654752440f;
    if constexpr (SGN > 0) { tr = c * (bi - br);  ti = -c * (br + bi); }
    else                   { tr = -c * (br + bi); ti = c * (br - bi);  }
  } else {
    constexpr float c1 = 0.92387953251128675613f;   // cos(pi/8)
    constexpr float s1 = 0.38268343236508977173f;   // sin(pi/8)
    constexpr float wr = (T == 1) ? c1 : (T == 3) ? s1 : (T == 5) ? -s1 : -c1;
    constexpr float wi0 = (T == 1) ? -s1 : (T == 3) ? -c1 : (T == 5) ? -c1 : -s1;
    constexpr float wi = (SGN > 0) ? wi0 : -wi0;
    tr = br * wr - bi * wi;
    ti = br * wi + bi * wr;
  }
  br = ar - tr;
  bi = ai - ti;
  ar = ar + tr;
  ai = ai + ti;
}

template <int SGN>
__device__ __forceinline__ void fft16(float re[16], float im[16]) {
#define SW_(a, b)                              \
  { float t = re[a]; re[a] = re[b]; re[b] = t; \
    t = im[a]; im[a] = im[b]; im[b] = t; }
  SW_(1, 8) SW_(2, 4) SW_(3, 12) SW_(5, 10) SW_(7, 14) SW_(11, 13)
#undef SW_
#define BF_(a, b, T) bfly<SGN, T>(re[a], im[a], re[b], im[b]);
  BF_(0, 1, 0) BF_(2, 3, 0) BF_(4, 5, 0) BF_(6, 7, 0)
  BF_(8, 9, 0) BF_(10, 11, 0) BF_(12, 13, 0) BF_(14, 15, 0)
  BF_(0, 2, 0) BF_(1, 3, 4) BF_(4, 6, 0) BF_(5, 7, 4)
  BF_(8, 10, 0) BF_(9, 11, 4) BF_(12, 14, 0) BF_(13, 15, 4)
  BF_(0, 4, 0) BF_(1, 5, 2) BF_(2, 6, 4) BF_(3, 7, 6)
  BF_(8, 12, 0) BF_(9, 13, 2) BF_(10, 14, 4) BF_(11, 15, 6)
  BF_(0, 8, 0) BF_(1, 9, 1) BF_(2, 10, 2) BF_(3, 11, 3)
  BF_(4, 12, 4) BF_(5, 13, 5) BF_(6, 14, 6) BF_(7, 15, 7)
#undef BF_
}

// COALESCED-STRIP kernel (round 8). Root cause of rounds 0-7's ~60us floor:
// thread-per-patch-row makes every global ld/st 64 scattered 16B requests per
// instruction (2KB lane stride) -> TA serialization ~64 slots/instr, never
// hideable at the ~8 resident waves/CU. Fix: block = (image, nh, half-strip);
// stage a contiguous 16x256 strip through LDS so each wave VMEM instruction
// covers a contiguous 1KB span. LDS strip doubles as the transpose medium
// (the two explicit transposes of r0-r7 vanish).
// S uses its exact rank-6 separable form: S[j][k] = sum_m ay_m[j]*ax_m[k],
// ay tables in LDS (per patch 6x16), ax computed per column-thread.
__global__ __launch_bounds__(256) void psm_kernel(
    const float* __restrict__ x, const float* __restrict__ logits,
    const float* __restrict__ mu, const float* __restrict__ sigma,
    const float* __restrict__ bias, float* __restrict__ out) {
  __shared__ float xs[16 * SROW];    // re strip; also re spectrum
  __shared__ float zim[16 * SROW];   // im strip; also output strip
  __shared__ float ytab[16 * YROW];  // 16 patches x 6 y-vectors[16]

  const int tid = threadIdx.x;
  const int bid = blockIdx.x;
  const int half = bid & 1;        // which 256px half of the image row-strip
  const int nh = (bid >> 1) & 31;  // patch-row
  const int b = bid >> 6;          // image

  const size_t xbase =
      (size_t)b * (HH * WW) + (size_t)(nh * 16) * WW + (size_t)(half * 256);

  const int w = tid >> 6;      // wave id (0..3)
  const int colv = tid & 63;   // float4 column within strip row

  // ---- stage-in: 4 coalesced float4 loads (per wave-instr: contiguous 1KB)
  float4 v0, v1, v2, v3;
  {
    const float* src = x + xbase + (size_t)(colv * 4);
    v0 = *(const float4*)(src + (size_t)((0 * 4 + w) * WW));
    v1 = *(const float4*)(src + (size_t)((1 * 4 + w) * WW));
    v2 = *(const float4*)(src + (size_t)((2 * 4 + w) * WW));
    v3 = *(const float4*)(src + (size_t)((3 * 4 + w) * WW));
  }

  const int nwl = tid >> 4;  // patch within strip (= 16-thread group, quarter-wave)
  const int r = tid & 15;    // row index / j index / k index per phase
  const int pg = nh * 32 + half * 16 + nwl;  // global patch id

  // ---- Phase A: y-factor tables (wave-local per patch group); overlaps the
  //      in-flight stage-in loads ----
  {
    const float fyr = (float)(r < 8 ? r : r - 16) * (1.0f / 16.0f);
#pragma unroll
    for (int m = 0; m < 6; ++m) {
      const int q = m >> 1;
      const float muy = mu[(pg * QQ + q) * 2 + 0];
      const float isy = 1.0f / sigma[(pg * QQ + q) * 2 + 0];
      const float d = ((m & 1) ? (fyr + muy) : (fyr - muy)) * isy;
      ytab[nwl * YROW + m * 16 + r] = __expf(-0.5f * d * d);
    }
  }

  // ---- park staged rows in LDS ----
  {
    float* dst = &xs[colv * 4];
    *(float4*)(dst + (0 * 4 + w) * SROW) = v0;
    *(float4*)(dst + (1 * 4 + w) * SROW) = v1;
    *(float4*)(dst + (2 * 4 + w) * SROW) = v2;
    *(float4*)(dst + (3 * 4 + w) * SROW) = v3;
  }
  __syncthreads();  // barrier 1: strip visible to all waves

  // ---- forward row FFT: thread (nwl, r) owns row r of patch nwl ----
  float re[16], im[16];
  {
    const float* rb = &xs[r * SROW + nwl * 16];
#pragma unroll
    for (int c4 = 0; c4 < 4; ++c4) {
      const float4 t = *(const float4*)(rb + c4 * 4);
      re[c4 * 4 + 0] = t.x;
      re[c4 * 4 + 1] = t.y;
      re[c4 * 4 + 2] = t.z;
      re[c4 * 4 + 3] = t.w;
    }
  }
#pragma unroll
  for (int c = 0; c < 16; ++c) im[c] = 0.0f;
  fft16<1>(re, im);
  {
    float* rbr = &xs[r * SROW + nwl * 16];
    float* rbi = &zim[r * SROW + nwl * 16];
#pragma unroll
    for (int c4 = 0; c4 < 4; ++c4) {
      float4 a, bb;
      a.x = re[c4 * 4 + 0]; a.y = re[c4 * 4 + 1];
      a.z = re[c4 * 4 + 2]; a.w = re[c4 * 4 + 3];
      bb.x = im[c4 * 4 + 0]; bb.y = im[c4 * 4 + 1];
      bb.z = im[c4 * 4 + 2]; bb.w = im[c4 * 4 + 3];
      *(float4*)(rbr + c4 * 4) = a;
      *(float4*)(rbi + c4 * 4) = bb;
    }
  }
  wfence();  // wave-local: column readers are the same 16-thread group

  // ---- column phase: thread (nwl, k=r) owns column k of patch nwl ----
  // s[j] = sum_m ax_m * ay_m[j] (+ jitter/256), with wq/256 folded into ax.
  float s[16];
  {
    const float fxk = (float)(r < 8 ? r : r - 16) * (1.0f / 16.0f);
    const float l0 = logits[pg * QQ + 0];
    const float l1 = logits[pg * QQ + 1];
    const float l2 = logits[pg * QQ + 2];
    const float lm = fmaxf(l0, fmaxf(l1, l2));
    const float e0 = __expf(l0 - lm);
    const float e1 = __expf(l1 - lm);
    const float e2 = __expf(l2 - lm);
    const float inv = (1.0f / 256.0f) / (e0 + e1 + e2);
    float ax[6];
#pragma unroll
    for (int m = 0; m < 6; ++m) {
      const int q = m >> 1;
      const float mux = mu[(pg * QQ + q) * 2 + 1];
      const float isx = 1.0f / sigma[(pg * QQ + q) * 2 + 1];
      const float d = ((m & 1) ? (fxk + mux) : (fxk - mux)) * isx;
      const float wqv = ((q == 0) ? e0 : (q == 1) ? e1 : e2) * inv;
      ax[m] = wqv * __expf(-0.5f * d * d);
    }
    const float* yt = &ytab[nwl * YROW];
#pragma unroll
    for (int j4 = 0; j4 < 4; ++j4) {
      const float4 a0 = *(const float4*)(yt + 0 * 16 + j4 * 4);
      const float4 a1 = *(const float4*)(yt + 1 * 16 + j4 * 4);
      const float4 a2 = *(const float4*)(yt + 2 * 16 + j4 * 4);
      const float4 a3 = *(const float4*)(yt + 3 * 16 + j4 * 4);
      const float4 a4 = *(const float4*)(yt + 4 * 16 + j4 * 4);
      const float4 a5 = *(const float4*)(yt + 5 * 16 + j4 * 4);
      s[j4 * 4 + 0] = a0.x * ax[0] + a1.x * ax[1] + a2.x * ax[2] +
                      a3.x * ax[3] + a4.x * ax[4] + a5.x * ax[5] + 3.90625e-9f;
      s[j4 * 4 + 1] = a0.y * ax[0] + a1.y * ax[1] + a2.y * ax[2] +
                      a3.y * ax[3] + a4.y * ax[4] + a5.y * ax[5] + 3.90625e-9f;
      s[j4 * 4 + 2] = a0.z * ax[0] + a1.z * ax[1] + a2.z * ax[2] +
                      a3.z * ax[3] + a4.z * ax[4] + a5.z * ax[5] + 3.90625e-9f;
      s[j4 * 4 + 3] = a0.w * ax[0] + a1.w * ax[1] + a2.w * ax[2] +
                      a3.w * ax[3] + a4.w * ax[4] + a5.w * ax[5] + 3.90625e-9f;
    }
  }
  {
    const float* cbr = &xs[nwl * 16 + r];
    const float* cbi = &zim[nwl * 16 + r];
#pragma unroll
    for (int j = 0; j < 16; ++j) {
      re[j] = cbr[j * SROW];
      im[j] = cbi[j * SROW];
    }
  }
  fft16<1>(re, im);
#pragma unroll
  for (int j = 0; j < 16; ++j) {
    re[j] *= s[j];
    im[j] *= s[j];
  }
  fft16<-1>(re, im);
  {
    float* cbr = &xs[nwl * 16 + r];
    float* cbi = &zim[nwl * 16 + r];
#pragma unroll
    for (int j = 0; j < 16; ++j) {
      cbr[j * SROW] = re[j];
      cbi[j * SROW] = im[j];
    }
  }
  wfence();  // wave-local: row readers are the same group

  // ---- inverse row FFT + bias; write y into zim strip (reuse) ----
  {
    const float* rbr = &xs[r * SROW + nwl * 16];
    const float* rbi = &zim[r * SROW + nwl * 16];
#pragma unroll
    for (int c4 = 0; c4 < 4; ++c4) {
      const float4 t = *(const float4*)(rbr + c4 * 4);
      const float4 u = *(const float4*)(rbi + c4 * 4);
      re[c4 * 4 + 0] = t.x; re[c4 * 4 + 1] = t.y;
      re[c4 * 4 + 2] = t.z; re[c4 * 4 + 3] = t.w;
      im[c4 * 4 + 0] = u.x; im[c4 * 4 + 1] = u.y;
      im[c4 * 4 + 2] = u.z; im[c4 * 4 + 3] = u.w;
    }
  }
  fft16<-1>(re, im);
  {
    const float* brow = bias + (size_t)pg * 256 + (size_t)(r * 16);
    float* rbo = &zim[r * SROW + nwl * 16];
#pragma unroll
    for (int c4 = 0; c4 < 4; ++c4) {
      const float4 bv = *(const float4*)(brow + c4 * 4);
      float4 o;
      o.x = re[c4 * 4 + 0] + bv.x;
      o.y = re[c4 * 4 + 1] + bv.y;
      o.z = re[c4 * 4 + 2] + bv.z;
      o.w = re[c4 * 4 + 3] + bv.w;
      *(float4*)(rbo + c4 * 4) = o;
    }
  }
  __syncthreads();  // barrier 2: output strip complete

  // ---- stage-out: 4 coalesced float4 stores ----
  {
    float* dst = out + xbase + (size_t)(colv * 4);
    const float* srcl = &zim[colv * 4];
#pragma unroll
    for (int j = 0; j < 4; ++j) {
      const float4 t = *(const float4*)(srcl + (j * 4 + w) * SROW);
      *(float4*)(dst + (size_t)((j * 4 + w) * WW)) = t;
    }
  }
}

extern "C" void kernel_launch(void* const* d_in, const int* in_sizes, int n_in,
                              void* d_out, int out_size, void* d_ws,
                              size_t ws_size, hipStream_t stream) {
  (void)in_sizes;
  (void)n_in;
  (void)out_size;
  (void)d_ws;
  (void)ws_size;
  const float* x = (const float*)d_in[0];
  const float* logits = (const float*)d_in[1];
  const float* mu = (const float*)d_in[2];
  const float* sigma = (const float*)d_in[3];
  const float* bias = (const float*)d_in[4];
  float* out = (float*)d_out;

  // 64 images x 32 patch-rows x 2 half-strips = 4096 blocks.
  psm_kernel<<<dim3(64 * 32 * 2), dim3(256), 0, stream>>>(x, logits, mu, sigma,
                                                          bias, out);
}

// Round 10
// 123.921 us; speedup vs baseline: 1.2696x; 1.0729x over previous
//
#include <hip/hip_runtime.h>
#include <math.h>

#define HH 512
#define WW 512
#define QQ 3

// LDS strip geometry: 16 rows x 256 px, row stride 260 floats (+4 pad).
#define SROW 260
// ytab per-patch stride: 6 vectors x 16 + 8 pad.
#define YROW 104

// Compiler-only memory fence: orders LDS ops (IR + sched chain edges) without
// pinning all code motion (sched_barrier(0) caused pressure spills, r3/r4).
// HW guarantee: one wave's LDS ops complete in issue order; the row<->column
// data exchange is within a 16-thread quarter-wave group (proven r5/r9).
__device__ __forceinline__ void wfence() { asm volatile("" ::: "memory"); }

// Butterfly with compile-time twiddle index T (0..7), radix-2 DIT, n=16.
template <int SGN, int T>
__device__ __forceinline__ void bfly(float& ar, float& ai, float& br, float& bi) {
  float tr, ti;
  if constexpr (T == 0) {
    tr = br;
    ti = bi;
  } else if constexpr (T == 4) {
    if constexpr (SGN > 0) { tr = bi;  ti = -br; }
    else                   { tr = -bi; ti = br;  }
  } else if constexpr (T == 2) {
    constexpr float c = 0.70710678118654752440f;
    if constexpr (SGN > 0) { tr = c * (br + bi); ti = c * (bi - br); }
    else                   { tr = c * (br - bi); ti = c * (bi + br); }
  } else if constexpr (T == 6) {
    constexpr float c = 0.70710678118654752440f;
    if constexpr (SGN > 0) { tr = c * (bi - br);  ti = -c * (br + bi); }
    else                   { tr = -c * (br + bi); ti = c * (br - bi);  }
  } else {
    constexpr float c1 = 0.92387953251128675613f;   // cos(pi/8)
    constexpr float s1 = 0.38268343236508977173f;   // sin(pi/8)
    constexpr float wr = (T == 1) ? c1 : (T == 3) ? s1 : (T == 5) ? -s1 : -c1;
    constexpr float wi0 = (T == 1) ? -s1 : (T == 3) ? -c1 : (T == 5) ? -c1 : -s1;
    constexpr float wi = (SGN > 0) ? wi0 : -wi0;
    tr = br * wr - bi * wi;
    ti = br * wi + bi * wr;
  }
  br = ar - tr;
  bi = ai - ti;
  ar = ar + tr;
  ai = ai + ti;
}

template <int SGN>
__device__ __forceinline__ void fft16(float re[16], float im[16]) {
#define SW_(a, b)                              \
  { float t = re[a]; re[a] = re[b]; re[b] = t; \
    t = im[a]; im[a] = im[b]; im[b] = t; }
  SW_(1, 8) SW_(2, 4) SW_(3, 12) SW_(5, 10) SW_(7, 14) SW_(11, 13)
#undef SW_
#define BF_(a, b, T) bfly<SGN, T>(re[a], im[a], re[b], im[b]);
  BF_(0, 1, 0) BF_(2, 3, 0) BF_(4, 5, 0) BF_(6, 7, 0)
  BF_(8, 9, 0) BF_(10, 11, 0) BF_(12, 13, 0) BF_(14, 15, 0)
  BF_(0, 2, 0) BF_(1, 3, 4) BF_(4, 6, 0) BF_(5, 7, 4)
  BF_(8, 10, 0) BF_(9, 11, 4) BF_(12, 14, 0) BF_(13, 15, 4)
  BF_(0, 4, 0) BF_(1, 5, 2) BF_(2, 6, 4) BF_(3, 7, 6)
  BF_(8, 12, 0) BF_(9, 13, 2) BF_(10, 14, 4) BF_(11, 15, 6)
  BF_(0, 8, 0) BF_(1, 9, 1) BF_(2, 10, 2) BF_(3, 11, 3)
  BF_(4, 12, 4) BF_(5, 13, 5) BF_(6, 14, 6) BF_(7, 15, 7)
#undef BF_
}

// COALESCED STRIP (r9, proven: dur 64->46us) + COMPLEX PACKING (r7, proven
// exact: S is 2D-even bit-exactly, so IFFT2(S o FFT2(xA + i*xB)) = yA + i*yB;
// absmax 0.16 passed). Block = (image-pair, patch-row, half-strip): stage
// image A's 16x256 strip into re (xs) and image B's into im (zim); run ONE
// complex pipeline; Re->A, Im->B at the store. The pair shares the patch, so
// the rank-6 separable S and ytab amortize 2x as well. Blocks halve to 2048:
// per-dispatch VALU and LDS (incl. the 4.69M b128 2-way conflicts) halve,
// HBM unchanged (~100MB -> ~16us floor).
__global__ __launch_bounds__(256) void psm_kernel(
    const float* __restrict__ x, const float* __restrict__ logits,
    const float* __restrict__ mu, const float* __restrict__ sigma,
    const float* __restrict__ bias, float* __restrict__ out) {
  __shared__ float xs[16 * SROW];    // image-A strip = Re; later yA strip
  __shared__ float zim[16 * SROW];   // image-B strip = Im; later yB strip
  __shared__ float ytab[16 * YROW];  // 16 patches x 6 y-vectors[16]

  const int tid = threadIdx.x;
  const int bid = blockIdx.x;
  const int half = bid & 1;        // which 256px half of the image row-strip
  const int nh = (bid >> 1) & 31;  // patch-row
  const int pr = bid >> 6;         // image pair (0..31)

  const size_t xbaseA = (size_t)(2 * pr) * (HH * WW) +
                        (size_t)(nh * 16) * WW + (size_t)(half * 256);
  const size_t xbaseB = xbaseA + (size_t)(HH * WW);

  const int w = tid >> 6;     // wave id (0..3)
  const int colv = tid & 63;  // float4 column within strip row

  // ---- stage-in: 8 coalesced float4 loads (A rows then B rows), all issued
  //      before any use so the 8 loads are concurrently in flight ----
  float4 a0, a1, a2, a3, b0, b1, b2, b3;
  {
    const float* srcA = x + xbaseA + (size_t)(colv * 4);
    const float* srcB = x + xbaseB + (size_t)(colv * 4);
    a0 = *(const float4*)(srcA + (size_t)((0 * 4 + w) * WW));
    a1 = *(const float4*)(srcA + (size_t)((1 * 4 + w) * WW));
    a2 = *(const float4*)(srcA + (size_t)((2 * 4 + w) * WW));
    a3 = *(const float4*)(srcA + (size_t)((3 * 4 + w) * WW));
    b0 = *(const float4*)(srcB + (size_t)((0 * 4 + w) * WW));
    b1 = *(const float4*)(srcB + (size_t)((1 * 4 + w) * WW));
    b2 = *(const float4*)(srcB + (size_t)((2 * 4 + w) * WW));
    b3 = *(const float4*)(srcB + (size_t)((3 * 4 + w) * WW));
  }

  const int nwl = tid >> 4;  // patch within strip (16-thread quarter-wave)
  const int r = tid & 15;    // row / j / k index depending on phase
  const int pg = nh * 32 + half * 16 + nwl;  // global patch id

  // ---- Phase A: y-factor tables; overlaps the in-flight stage loads ----
  {
    const float fyr = (float)(r < 8 ? r : r - 16) * (1.0f / 16.0f);
#pragma unroll
    for (int m = 0; m < 6; ++m) {
      const int q = m >> 1;
      const float muy = mu[(pg * QQ + q) * 2 + 0];
      const float isy = 1.0f / sigma[(pg * QQ + q) * 2 + 0];
      const float d = ((m & 1) ? (fyr + muy) : (fyr - muy)) * isy;
      ytab[nwl * YROW + m * 16 + r] = __expf(-0.5f * d * d);
    }
  }

  // ---- park staged rows in LDS ----
  {
    float* dstA = &xs[colv * 4];
    float* dstB = &zim[colv * 4];
    *(float4*)(dstA + (0 * 4 + w) * SROW) = a0;
    *(float4*)(dstA + (1 * 4 + w) * SROW) = a1;
    *(float4*)(dstA + (2 * 4 + w) * SROW) = a2;
    *(float4*)(dstA + (3 * 4 + w) * SROW) = a3;
    *(float4*)(dstB + (0 * 4 + w) * SROW) = b0;
    *(float4*)(dstB + (1 * 4 + w) * SROW) = b1;
    *(float4*)(dstB + (2 * 4 + w) * SROW) = b2;
    *(float4*)(dstB + (3 * 4 + w) * SROW) = b3;
  }
  __syncthreads();  // barrier 1: both strips visible to all waves

  // ---- forward row FFT: thread (nwl, r) owns row r of patch nwl;
  //      re = image A row, im = image B row (complex packing) ----
  float re[16], im[16];
  {
    const float* rbr = &xs[r * SROW + nwl * 16];
    const float* rbi = &zim[r * SROW + nwl * 16];
#pragma unroll
    for (int c4 = 0; c4 < 4; ++c4) {
      const float4 t = *(const float4*)(rbr + c4 * 4);
      const float4 u = *(const float4*)(rbi + c4 * 4);
      re[c4 * 4 + 0] = t.x; re[c4 * 4 + 1] = t.y;
      re[c4 * 4 + 2] = t.z; re[c4 * 4 + 3] = t.w;
      im[c4 * 4 + 0] = u.x; im[c4 * 4 + 1] = u.y;
      im[c4 * 4 + 2] = u.z; im[c4 * 4 + 3] = u.w;
    }
  }
  fft16<1>(re, im);
  {
    float* rbr = &xs[r * SROW + nwl * 16];
    float* rbi = &zim[r * SROW + nwl * 16];
#pragma unroll
    for (int c4 = 0; c4 < 4; ++c4) {
      float4 a, bb;
      a.x = re[c4 * 4 + 0]; a.y = re[c4 * 4 + 1];
      a.z = re[c4 * 4 + 2]; a.w = re[c4 * 4 + 3];
      bb.x = im[c4 * 4 + 0]; bb.y = im[c4 * 4 + 1];
      bb.z = im[c4 * 4 + 2]; bb.w = im[c4 * 4 + 3];
      *(float4*)(rbr + c4 * 4) = a;
      *(float4*)(rbi + c4 * 4) = bb;
    }
  }
  wfence();  // wave-local handoff (column readers = same 16-thread group)

  // ---- column phase: thread (nwl, k=r) owns column k of patch nwl ----
  // s[j] = sum_m ax_m * ay_m[j] (+ jitter/256), wq/256 folded into ax.
  float s[16];
  {
    const float fxk = (float)(r < 8 ? r : r - 16) * (1.0f / 16.0f);
    const float l0 = logits[pg * QQ + 0];
    const float l1 = logits[pg * QQ + 1];
    const float l2 = logits[pg * QQ + 2];
    const float lm = fmaxf(l0, fmaxf(l1, l2));
    const float e0 = __expf(l0 - lm);
    const float e1 = __expf(l1 - lm);
    const float e2 = __expf(l2 - lm);
    const float inv = (1.0f / 256.0f) / (e0 + e1 + e2);
    float ax[6];
#pragma unroll
    for (int m = 0; m < 6; ++m) {
      const int q = m >> 1;
      const float mux = mu[(pg * QQ + q) * 2 + 1];
      const float isx = 1.0f / sigma[(pg * QQ + q) * 2 + 1];
      const float d = ((m & 1) ? (fxk + mux) : (fxk - mux)) * isx;
      const float wqv = ((q == 0) ? e0 : (q == 1) ? e1 : e2) * inv;
      ax[m] = wqv * __expf(-0.5f * d * d);
    }
    const float* yt = &ytab[nwl * YROW];
#pragma unroll
    for (int j4 = 0; j4 < 4; ++j4) {
      const float4 a0v = *(const float4*)(yt + 0 * 16 + j4 * 4);
      const float4 a1v = *(const float4*)(yt + 1 * 16 + j4 * 4);
      const float4 a2v = *(const float4*)(yt + 2 * 16 + j4 * 4);
      const float4 a3v = *(const float4*)(yt + 3 * 16 + j4 * 4);
      const float4 a4v = *(const float4*)(yt + 4 * 16 + j4 * 4);
      const float4 a5v = *(const float4*)(yt + 5 * 16 + j4 * 4);
      s[j4 * 4 + 0] = a0v.x * ax[0] + a1v.x * ax[1] + a2v.x * ax[2] +
                      a3v.x * ax[3] + a4v.x * ax[4] + a5v.x * ax[5] + 3.90625e-9f;
      s[j4 * 4 + 1] = a0v.y * ax[0] + a1v.y * ax[1] + a2v.y * ax[2] +
                      a3v.y * ax[3] + a4v.y * ax[4] + a5v.y * ax[5] + 3.90625e-9f;
      s[j4 * 4 + 2] = a0v.z * ax[0] + a1v.z * ax[1] + a2v.z * ax[2] +
                      a3v.z * ax[3] + a4v.z * ax[4] + a5v.z * ax[5] + 3.90625e-9f;
      s[j4 * 4 + 3] = a0v.w * ax[0] + a1v.w * ax[1] + a2v.w * ax[2] +
                      a3v.w * ax[3] + a4v.w * ax[4] + a5v.w * ax[5] + 3.90625e-9f;
    }
  }
  {
    const float* cbr = &xs[nwl * 16 + r];
    const float* cbi = &zim[nwl * 16 + r];
#pragma unroll
    for (int j = 0; j < 16; ++j) {
      re[j] = cbr[j * SROW];
      im[j] = cbi[j * SROW];
    }
  }
  fft16<1>(re, im);
#pragma unroll
  for (int j = 0; j < 16; ++j) {
    re[j] *= s[j];
    im[j] *= s[j];
  }
  fft16<-1>(re, im);
  {
    float* cbr = &xs[nwl * 16 + r];
    float* cbi = &zim[nwl * 16 + r];
#pragma unroll
    for (int j = 0; j < 16; ++j) {
      cbr[j * SROW] = re[j];
      cbi[j * SROW] = im[j];
    }
  }
  wfence();  // wave-local handoff (row readers = same group)

  // ---- inverse row FFT; Re -> yA, Im -> yB; +bias; back into strips ----
  {
    const float* rbr = &xs[r * SROW + nwl * 16];
    const float* rbi = &zim[r * SROW + nwl * 16];
#pragma unroll
    for (int c4 = 0; c4 < 4; ++c4) {
      const float4 t = *(const float4*)(rbr + c4 * 4);
      const float4 u = *(const float4*)(rbi + c4 * 4);
      re[c4 * 4 + 0] = t.x; re[c4 * 4 + 1] = t.y;
      re[c4 * 4 + 2] = t.z; re[c4 * 4 + 3] = t.w;
      im[c4 * 4 + 0] = u.x; im[c4 * 4 + 1] = u.y;
      im[c4 * 4 + 2] = u.z; im[c4 * 4 + 3] = u.w;
    }
  }
  fft16<-1>(re, im);
  {
    const float* brow = bias + (size_t)pg * 256 + (size_t)(r * 16);
    float* rba = &xs[r * SROW + nwl * 16];
    float* rbb = &zim[r * SROW + nwl * 16];
#pragma unroll
    for (int c4 = 0; c4 < 4; ++c4) {
      const float4 bv = *(const float4*)(brow + c4 * 4);
      float4 oA, oB;
      oA.x = re[c4 * 4 + 0] + bv.x;
      oA.y = re[c4 * 4 + 1] + bv.y;
      oA.z = re[c4 * 4 + 2] + bv.z;
      oA.w = re[c4 * 4 + 3] + bv.w;
      oB.x = im[c4 * 4 + 0] + bv.x;
      oB.y = im[c4 * 4 + 1] + bv.y;
      oB.z = im[c4 * 4 + 2] + bv.z;
      oB.w = im[c4 * 4 + 3] + bv.w;
      *(float4*)(rba + c4 * 4) = oA;
      *(float4*)(rbb + c4 * 4) = oB;
    }
  }
  __syncthreads();  // barrier 2: output strips complete

  // ---- stage-out: 8 coalesced float4 stores ----
  {
    float* dstA = out + xbaseA + (size_t)(colv * 4);
    float* dstB = out + xbaseB + (size_t)(colv * 4);
    const float* srcA = &xs[colv * 4];
    const float* srcB = &zim[colv * 4];
#pragma unroll
    for (int j = 0; j < 4; ++j) {
      const float4 tA = *(const float4*)(srcA + (j * 4 + w) * SROW);
      *(float4*)(dstA + (size_t)((j * 4 + w) * WW)) = tA;
    }
#pragma unroll
    for (int j = 0; j < 4; ++j) {
      const float4 tB = *(const float4*)(srcB + (j * 4 + w) * SROW);
      *(float4*)(dstB + (size_t)((j * 4 + w) * WW)) = tB;
    }
  }
}

extern "C" void kernel_launch(void* const* d_in, const int* in_sizes, int n_in,
                              void* d_out, int out_size, void* d_ws,
                              size_t ws_size, hipStream_t stream) {
  (void)in_sizes;
  (void)n_in;
  (void)out_size;
  (void)d_ws;
  (void)ws_size;
  const float* x = (const float*)d_in[0];
  const float* logits = (const float*)d_in[1];
  const float* mu = (const float*)d_in[2];
  const float* sigma = (const float*)d_in[3];
  const float* bias = (const float*)d_in[4];
  float* out = (float*)d_out;

  // 32 image-pairs x 32 patch-rows x 2 half-strips = 2048 blocks.
  psm_kernel<<<dim3(32 * 32 * 2), dim3(256), 0, stream>>>(x, logits, mu, sigma,
                                                          bias, out);
}